// Round 6
// baseline (811.963 us; speedup 1.0000x reference)
//
#include <hip/hip_runtime.h>
#include <hip/hip_bf16.h>
#include <math.h>

typedef unsigned short u16;
typedef __attribute__((ext_vector_type(8))) short short8;   // 8 x bf16 (4 VGPRs)
typedef __attribute__((ext_vector_type(4))) float f32x4;

static constexpr int NB = 4, NS = 192, ND = 512, NHD = 8, NDK = 64, NFF = 2048, NLAY = 2;
static constexpr int NQKV = 3 * ND;   // 1536
static constexpr float EPSV = 1e-6f;

__device__ __forceinline__ u16 f2bf(float f) {
  union { float f; unsigned u; } c; c.f = f;
  unsigned x = c.u;
  return (u16)((x + 0x7fffu + ((x >> 16) & 1u)) >> 16);
}

// ---------------- weight transpose (K,N) f32 -> (N,K) bf16, per layer (blockIdx.z) ----
__global__ __launch_bounds__(256) void wt_transpose(const float* __restrict__ src,
                                                    u16* __restrict__ dst, int K, int N) {
  __shared__ float tile[32][33];
  const int l = blockIdx.z;
  src += (size_t)l * K * N;
  dst += (size_t)l * K * N;
  const int n0 = blockIdx.x * 32, k0 = blockIdx.y * 32;
  const int tx = threadIdx.x & 31, ty = threadIdx.x >> 5;   // ty: 0..7
#pragma unroll
  for (int ii = 0; ii < 4; ++ii)
    tile[ty + ii * 8][tx] = src[(size_t)(k0 + ty + ii * 8) * N + n0 + tx];
  __syncthreads();
#pragma unroll
  for (int ii = 0; ii < 4; ++ii) {
    const int n = ty + ii * 8;
    dst[(size_t)(n0 + n) * K + k0 + tx] = f2bf(tile[tx][n]);
  }
}

// packed QKV transpose: dst is per-layer (1536, 512) bf16 = [Wq^T; Wk^T; Wv^T]
__global__ __launch_bounds__(256) void wt_transpose_qkv(const float* __restrict__ Wq,
                                                        const float* __restrict__ Wk,
                                                        const float* __restrict__ Wv,
                                                        u16* __restrict__ dst) {
  __shared__ float tile[32][33];
  const int z = blockIdx.z;                 // l*3 + which
  const int l = z / 3, which = z - l * 3;
  const float* src = (which == 0 ? Wq : which == 1 ? Wk : Wv) + (size_t)l * ND * ND;
  u16* d = dst + (size_t)z * ND * ND;       // rows [which*512, which*512+512) of layer l
  const int n0 = blockIdx.x * 32, k0 = blockIdx.y * 32;
  const int tx = threadIdx.x & 31, ty = threadIdx.x >> 5;
#pragma unroll
  for (int ii = 0; ii < 4; ++ii)
    tile[ty + ii * 8][tx] = src[(size_t)(k0 + ty + ii * 8) * ND + n0 + tx];
  __syncthreads();
#pragma unroll
  for (int ii = 0; ii < 4; ++ii) {
    const int n = ty + ii * 8;
    d[(size_t)(n0 + n) * ND + k0 + tx] = f2bf(tile[tx][n]);
  }
}

// ---------------- layernorm (torch semantics: ddof=1, a*(x-mu)/(sd+eps)+b) -----------
template<bool BF16OUT>
__global__ __launch_bounds__(256) void norm_kernel(const float* __restrict__ x,
                                                   const float* __restrict__ alpha,
                                                   const float* __restrict__ beta,
                                                   void* __restrict__ outp) {
  const int row = blockIdx.x;
  const int tid = threadIdx.x;
  const float2 v = *(const float2*)(x + (size_t)row * ND + tid * 2);
  float s = v.x + v.y;
  float q = v.x * v.x + v.y * v.y;
#pragma unroll
  for (int m = 1; m < 64; m <<= 1) { s += __shfl_xor(s, m, 64); q += __shfl_xor(q, m, 64); }
  __shared__ float ss[4], sq[4];
  const int wid = tid >> 6;
  if ((tid & 63) == 0) { ss[wid] = s; sq[wid] = q; }
  __syncthreads();
  s = ss[0] + ss[1] + ss[2] + ss[3];
  q = sq[0] + sq[1] + sq[2] + sq[3];
  const float mu = s * (1.0f / ND);
  const float var = (q - (float)ND * mu * mu) * (1.0f / (ND - 1));
  const float sd = sqrtf(fmaxf(var, 0.0f));
  const float inv = 1.0f / (sd + EPSV);
  const float a0 = alpha[tid * 2], a1 = alpha[tid * 2 + 1];
  const float g0 = beta[tid * 2],  g1 = beta[tid * 2 + 1];
  const float y0 = (v.x - mu) * inv * a0 + g0;
  const float y1 = (v.y - mu) * inv * a1 + g1;
  if (BF16OUT) {
    ushort2 o; o.x = f2bf(y0); o.y = f2bf(y1);
    *(ushort2*)((u16*)outp + (size_t)row * ND + tid * 2) = o;
  } else {
    float2 o; o.x = y0; o.y = y1;
    *(float2*)((float*)outp + (size_t)row * ND + tid * 2) = o;
  }
}

// ---------------- bf16 MFMA GEMM: C[M,N] = A[M,K] * Bt[N,K]^T (+bias, modes) ---------
// MODE 0: f32 out.  MODE 1: relu + bf16 out.  MODE 2: f32 out + residual.
// MODE 3: f32 out, 3-way packed bias (qkv: n<512 -> bias, <1024 -> bias2, else bias3).
template<int MODE>
__global__ __launch_bounds__(256) void gemm_kernel(const u16* __restrict__ A,
                                                   const u16* __restrict__ Bt,
                                                   const float* __restrict__ bias,
                                                   const float* __restrict__ bias2,
                                                   const float* __restrict__ bias3,
                                                   const float* __restrict__ res,
                                                   void* __restrict__ outp,
                                                   int M, int N, int K) {
  __shared__ u16 lA[64 * 64];
  __shared__ u16 lB[64 * 64];
  const int tid = threadIdx.x;
  const int lane = tid & 63;
  const int wid = tid >> 6;
  const int m0 = blockIdx.y * 64;
  const int n0 = blockIdx.x * 64;
  const int wr = (wid >> 1) * 32;   // wave's 32x32 quadrant
  const int wc = (wid & 1) * 32;

  f32x4 acc[2][2] = {};

  for (int k0 = 0; k0 < K; k0 += 64) {
    // stage 64x64 bf16 tiles; 16B chunks; XOR-swizzle chunk within row (G4)
#pragma unroll
    for (int half = 0; half < 2; ++half) {
      const int cid = tid + half * 256;          // 0..511
      const int r = cid >> 3, c = cid & 7;
      const int cs = c ^ (r & 7);
      const int4 va = *(const int4*)(A + (size_t)(m0 + r) * K + k0 + c * 8);
      *(int4*)(lA + r * 64 + cs * 8) = va;
      const int4 vb = *(const int4*)(Bt + (size_t)(n0 + r) * K + k0 + c * 8);
      *(int4*)(lB + r * 64 + cs * 8) = vb;
    }
    __syncthreads();
    short8 af[2][2], bfr[2][2];
#pragma unroll
    for (int fr = 0; fr < 2; ++fr)
#pragma unroll
      for (int kc = 0; kc < 2; ++kc) {
        const int ch = kc * 4 + (lane >> 4);
        const int ra = wr + fr * 16 + (lane & 15);
        af[fr][kc] = *(const short8*)(lA + ra * 64 + (ch ^ (ra & 7)) * 8);
        const int rb = wc + fr * 16 + (lane & 15);
        bfr[fr][kc] = *(const short8*)(lB + rb * 64 + (ch ^ (rb & 7)) * 8);
      }
#pragma unroll
    for (int kc = 0; kc < 2; ++kc)
#pragma unroll
      for (int fr = 0; fr < 2; ++fr)
#pragma unroll
        for (int fc = 0; fc < 2; ++fc)
          acc[fr][fc] = __builtin_amdgcn_mfma_f32_16x16x32_bf16(af[fr][kc], bfr[fc][kc],
                                                                acc[fr][fc], 0, 0, 0);
    __syncthreads();
  }
  // epilogue: C/D layout col=lane&15, row=(lane>>4)*4+reg (verified m89)
#pragma unroll
  for (int fr = 0; fr < 2; ++fr)
#pragma unroll
    for (int fc = 0; fc < 2; ++fc)
#pragma unroll
      for (int reg = 0; reg < 4; ++reg) {
        const int m = m0 + wr + fr * 16 + (lane >> 4) * 4 + reg;
        const int n = n0 + wc + fc * 16 + (lane & 15);
        float bval;
        if (MODE == 3) bval = (n < ND) ? bias[n] : (n < 2 * ND ? bias2[n - ND] : bias3[n - 2 * ND]);
        else           bval = bias[n];
        float v = acc[fr][fc][reg] + bval;
        if (MODE == 1) v = fmaxf(v, 0.0f);
        if (MODE == 2) v += res[(size_t)m * N + n];
        if (MODE == 1) ((u16*)outp)[(size_t)m * N + n] = f2bf(v);
        else           ((float*)outp)[(size_t)m * N + n] = v;
      }
}

// ---------------- fused edge-bias attention: one block per (b, i) --------------------
// qkv: (B*S, 1536) f32 rows = [q | k | v].  wave = head; 4 groups of 16 lanes;
// group g owns j = g (mod 4); lane covers 4 d's via float4.
__global__ __launch_bounds__(512) void attn_kernel(const float* __restrict__ qkv,
                                                   const float* __restrict__ ebk,
                                                   const float* __restrict__ ebv,
                                                   const int* __restrict__ mask,
                                                   u16* __restrict__ outp) {
  const int bi = blockIdx.x;
  const int b = bi / NS, i = bi % NS;
  const int tid = threadIdx.x;
  const int h = tid >> 6;
  const int lane = tid & 63;
  const int g = lane >> 4;
  const int t = lane & 15;

  __shared__ float sp[NHD][NS];   // scores then probs (per-wave private row)

  const float4 qv = *(const float4*)(qkv + (size_t)bi * NQKV + h * NDK + t * 4);
  const float scale = 0.125f;     // 1/sqrt(64)
  // reference: mask[:,None,:,None]==1 broadcasts onto the QUERY axis (i), over all j
  const bool row_masked = (mask[b * NS + i] == 1);

#pragma unroll 4
  for (int j = g; j < NS; j += 4) {
    const float4 kv = *(const float4*)(qkv + ((size_t)(b * NS + j)) * NQKV + ND + h * NDK + t * 4);
    // edge-bias: stream-once data (604 MB total > L3) -> non-temporal, don't evict K/V
    const f32x4 ev = __builtin_nontemporal_load(
        (const f32x4*)(ebk + (((size_t)(b * NS + j)) * NS + i) * ND + h * NDK + t * 4));
    float part = qv.x * (kv.x + ev.x) + qv.y * (kv.y + ev.y)
               + qv.z * (kv.z + ev.z) + qv.w * (kv.w + ev.w);
    part += __shfl_xor(part, 1);
    part += __shfl_xor(part, 2);
    part += __shfl_xor(part, 4);
    part += __shfl_xor(part, 8);
    if (t == 0) {
      float s = part * scale;
      if (row_masked) s = -1e9f;
      sp[h][j] = s;
    }
  }
  __syncthreads();
  // softmax over 192 j (per wave)
  float s0 = sp[h][lane], s1 = sp[h][lane + 64], s2 = sp[h][lane + 128];
  float mx = fmaxf(fmaxf(s0, s1), s2);
#pragma unroll
  for (int m = 1; m < 64; m <<= 1) mx = fmaxf(mx, __shfl_xor(mx, m));
  const float e0 = __expf(s0 - mx), e1 = __expf(s1 - mx), e2 = __expf(s2 - mx);
  float sum = e0 + e1 + e2;
#pragma unroll
  for (int m = 1; m < 64; m <<= 1) sum += __shfl_xor(sum, m);
  const float inv = 1.0f / sum;
  sp[h][lane] = e0 * inv; sp[h][lane + 64] = e1 * inv; sp[h][lane + 128] = e2 * inv;
  __syncthreads();
  // PV + edge-bias-V
  float4 acc = {0.f, 0.f, 0.f, 0.f};
#pragma unroll 4
  for (int j = g; j < NS; j += 4) {
    const float4 vv = *(const float4*)(qkv + ((size_t)(b * NS + j)) * NQKV + 2 * ND + h * NDK + t * 4);
    const f32x4 ev = __builtin_nontemporal_load(
        (const f32x4*)(ebv + (((size_t)(b * NS + j)) * NS + i) * ND + h * NDK + t * 4));
    const float pj = sp[h][j];
    acc.x += pj * (vv.x + ev.x);
    acc.y += pj * (vv.y + ev.y);
    acc.z += pj * (vv.z + ev.z);
    acc.w += pj * (vv.w + ev.w);
  }
#pragma unroll
  for (int m = 16; m < 64; m <<= 1) {
    acc.x += __shfl_xor(acc.x, m);
    acc.y += __shfl_xor(acc.y, m);
    acc.z += __shfl_xor(acc.z, m);
    acc.w += __shfl_xor(acc.w, m);
  }
  if (g == 0) {
    ushort4 o = make_ushort4(f2bf(acc.x), f2bf(acc.y), f2bf(acc.z), f2bf(acc.w));
    *(ushort4*)(outp + (size_t)bi * ND + h * NDK + t * 4) = o;
  }
}

// -------------------------------------------------------------------------------------
extern "C" void kernel_launch(void* const* d_in, const int* in_sizes, int n_in,
                              void* d_out, int out_size, void* d_ws, size_t ws_size,
                              hipStream_t stream) {
  const float* x    = (const float*)d_in[0];
  const float* ebk  = (const float*)d_in[1];
  const float* ebv  = (const float*)d_in[2];
  const int*   mask = (const int*)d_in[3];
  const float* Wq = (const float*)d_in[4];  const float* bq = (const float*)d_in[5];
  const float* Wk = (const float*)d_in[6];  const float* bk = (const float*)d_in[7];
  const float* Wv = (const float*)d_in[8];  const float* bv = (const float*)d_in[9];
  const float* Wo = (const float*)d_in[10]; const float* bo = (const float*)d_in[11];
  const float* n1a = (const float*)d_in[12]; const float* n1b = (const float*)d_in[13];
  const float* n2a = (const float*)d_in[14]; const float* n2b = (const float*)d_in[15];
  const float* W1 = (const float*)d_in[16]; const float* b1 = (const float*)d_in[17];
  const float* W2 = (const float*)d_in[18]; const float* b2 = (const float*)d_in[19];
  const float* fna = (const float*)d_in[20]; const float* fnb = (const float*)d_in[21];
  float* out = (float*)d_out;

  char* ws = (char*)d_ws;
  size_t off = 0;
  auto alloc = [&](size_t bytes) -> char* {
    char* p = ws + off;
    off = (off + bytes + 255) & ~(size_t)255;
    return p;
  };
  const size_t BSD = (size_t)NB * NS * ND;
  float* xcur  = (float*)alloc(BSD * 4);
  u16*   x2    = (u16*)  alloc(BSD * 2);
  float* qkvb  = (float*)alloc(BSD * 3 * 4);                 // (768, 1536) f32
  u16*   attnb = (u16*)  alloc(BSD * 2);
  u16*   mid   = (u16*)  alloc((size_t)NB * NS * NFF * 2);
  u16*   wqkv_t= (u16*)  alloc((size_t)NLAY * NQKV * ND * 2); // per-layer (1536,512)
  u16*   wo_t  = (u16*)  alloc((size_t)NLAY * ND * ND * 2);
  u16*   w1_t  = (u16*)  alloc((size_t)NLAY * ND * NFF * 2);
  u16*   w2_t  = (u16*)  alloc((size_t)NLAY * ND * NFF * 2);

  // weight transposes (re-done every call; ws is re-poisoned by harness)
  wt_transpose_qkv<<<dim3(ND / 32, ND / 32, NLAY * 3), 256, 0, stream>>>(Wq, Wk, Wv, wqkv_t);
  wt_transpose<<<dim3(ND / 32, ND / 32, NLAY), 256, 0, stream>>>(Wo, wo_t, ND, ND);
  wt_transpose<<<dim3(NFF / 32, ND / 32, NLAY), 256, 0, stream>>>(W1, w1_t, ND, NFF);
  wt_transpose<<<dim3(ND / 32, NFF / 32, NLAY), 256, 0, stream>>>(W2, w2_t, NFF, ND);

  const int M = NB * NS;   // 768
  for (int l = 0; l < NLAY; ++l) {
    const float* xin = (l == 0) ? x : xcur;
    norm_kernel<true><<<M, 256, 0, stream>>>(xin, n1a + l * ND, n1b + l * ND, x2);
    gemm_kernel<3><<<dim3(NQKV / 64, M / 64), 256, 0, stream>>>(
        x2, wqkv_t + (size_t)l * NQKV * ND, bq + l * ND, bk + l * ND, bv + l * ND,
        nullptr, qkvb, M, NQKV, ND);
    attn_kernel<<<M, 512, 0, stream>>>(qkvb, ebk, ebv, mask, attnb);
    gemm_kernel<2><<<dim3(ND / 64, M / 64), 256, 0, stream>>>(
        attnb, wo_t + (size_t)l * ND * ND, bo + l * ND, nullptr, nullptr, xin, xcur,
        M, ND, ND);
    norm_kernel<true><<<M, 256, 0, stream>>>(xcur, n2a + l * ND, n2b + l * ND, x2);
    gemm_kernel<1><<<dim3(NFF / 64, M / 64), 256, 0, stream>>>(
        x2, w1_t + (size_t)l * ND * NFF, b1 + l * NFF, nullptr, nullptr, nullptr, mid,
        M, NFF, ND);
    gemm_kernel<2><<<dim3(ND / 64, M / 64), 256, 0, stream>>>(
        mid, w2_t + (size_t)l * ND * NFF, b2 + l * ND, nullptr, nullptr, xcur, xcur,
        M, ND, NFF);
  }
  norm_kernel<false><<<M, 256, 0, stream>>>(xcur, fna, fnb, out);
}